// Round 1
// baseline (138.235 us; speedup 1.0000x reference)
//
#include <hip/hip_runtime.h>
#include <hip/hip_bf16.h>

// One wave (64 lanes) per batch. k_proj = k[24x512] x Wk^T is the heavy phase:
// Wk held in per-lane registers distributed by f; k rows loaded coalesced from
// global; cross-lane reduce via DPP (VALU pipe) to avoid DS-pipe pressure.

#define DPP_ADD(x, ctrl, rmask)                                                   \
  x += __int_as_float(__builtin_amdgcn_update_dpp(                                \
      0, __float_as_int(x), ctrl, rmask, 0xF, false))

__device__ __forceinline__ float wave_sum64(float x) {
  DPP_ADD(x, 0xB1, 0xF);   // quad_perm [1,0,3,2]  : xor 1
  DPP_ADD(x, 0x4E, 0xF);   // quad_perm [2,3,0,1]  : xor 2
  DPP_ADD(x, 0x141, 0xF);  // row_half_mirror      : xor 4 (after s1,s2)
  DPP_ADD(x, 0x140, 0xF);  // row_mirror           : xor 8 (after s1..s3)
  DPP_ADD(x, 0x142, 0xA);  // row_bcast15 -> rows 1,3
  DPP_ADD(x, 0x143, 0xC);  // row_bcast31 -> rows 2,3
  return x;                // full 64-lane sum valid in lanes 48..63
}

__global__ __launch_bounds__(64) void coattn_kernel(
    const float* __restrict__ q, const float* __restrict__ k,
    const float* __restrict__ Wq, const float* __restrict__ bq,
    const float* __restrict__ Wk, const float* __restrict__ bk,
    const float* __restrict__ Wl, const float* __restrict__ bl,
    float* __restrict__ out) {
  constexpr int QL = 24, KVL = 24, DQ = 12, DKV = 512;

  __shared__ float kp[KVL][DQ];        // k_proj
  __shared__ float qp[QL][DQ];         // q_proj
  __shared__ float qkbuf[QL][KVL];     // qk -> a_q (in place) -> c_k
  __shared__ float akT[KVL][QL];       // a_k transposed [k][q]
  __shared__ float qcb[QL][2 * DQ];    // [q | c_q]
  __shared__ float Wq_l[DQ * DQ];
  __shared__ float Wl_l[DQ * KVL];
  __shared__ float bql[DQ], bkl[DQ], bll[DQ];
  __shared__ float colmax[KVL], colrs[KVL], rowmax[QL], rowrs[QL];

  const int lane = threadIdx.x;
  const int b = blockIdx.x;

  // ---- preload constants into LDS ----
  for (int p = lane; p < DQ * DQ; p += 64) Wq_l[p] = Wq[p];
  for (int p = lane; p < DQ * KVL; p += 64) Wl_l[p] = Wl[p];
  if (lane < DQ) {
    bql[lane] = bq[lane];
    bkl[lane] = bk[lane];
    bll[lane] = bl[lane];
  }

  // ---- load q into qc[:, 0:12] ----
  const float* qb = q + (size_t)b * (QL * DQ);
  for (int p = lane; p < QL * DQ; p += 64) qcb[p / DQ][p % DQ] = qb[p];

  // ---- Wk into registers, distributed over lanes by f ----
  // lane l holds Wk[e][4l..4l+3] (wk0) and Wk[e][256+4l..256+4l+3] (wk1)
  const float4* WkV = reinterpret_cast<const float4*>(Wk);
  float4 wk0[DQ], wk1[DQ];
#pragma unroll
  for (int e = 0; e < DQ; ++e) {
    wk0[e] = WkV[e * 128 + lane];
    wk1[e] = WkV[e * 128 + 64 + lane];
  }

  __syncthreads();

  // ---- k_proj: per row, coalesced global load + per-lane FMA + DPP reduce ----
  const float4* kbV = reinterpret_cast<const float4*>(k + (size_t)b * (KVL * DKV));
  float4 ca = kbV[lane];
  float4 cb = kbV[64 + lane];
  for (int kv = 0; kv < KVL; ++kv) {
    const int nkv = (kv + 1 < KVL) ? kv + 1 : kv;  // prefetch next row
    float4 na = kbV[nkv * 128 + lane];
    float4 nb = kbV[nkv * 128 + 64 + lane];
    float pp[DQ];
#pragma unroll
    for (int e = 0; e < DQ; ++e) {
      pp[e] = ca.x * wk0[e].x + ca.y * wk0[e].y + ca.z * wk0[e].z + ca.w * wk0[e].w +
              cb.x * wk1[e].x + cb.y * wk1[e].y + cb.z * wk1[e].z + cb.w * wk1[e].w;
    }
#pragma unroll
    for (int e = 0; e < DQ; ++e) pp[e] = wave_sum64(pp[e]);
    if (lane == 63) {
#pragma unroll
      for (int e = 0; e < DQ; ++e) kp[kv][e] = pp[e] + bkl[e];
    }
    ca = na;
    cb = nb;
  }
  __syncthreads();

  // ---- q_proj[q][e] = bq[e] + sum_d q[q][d] * Wq[e][d] ----
  for (int p = lane; p < QL * DQ; p += 64) {
    const int r = p / DQ, e = p % DQ;
    float acc = bql[e];
#pragma unroll
    for (int d = 0; d < DQ; ++d) acc += qcb[r][d] * Wq_l[e * DQ + d];
    qp[r][e] = acc;
  }
  __syncthreads();

  // ---- qk[q][k] = sum_e q_proj[q][e] * k_proj[k][e] ----
  for (int p = lane; p < QL * KVL; p += 64) {
    const int r = p / KVL, kk = p % KVL;
    float acc = 0.f;
#pragma unroll
    for (int e = 0; e < DQ; ++e) acc += qp[r][e] * kp[kk][e];
    qkbuf[r][kk] = acc;
  }
  __syncthreads();

  // ---- softmax stats: columns (over q, for a_q) and rows (over k, for a_k) ----
  {
    const int idx = lane & 31;
    const bool isCol = lane < 32;
    if (idx < 24) {
      float m = -1e30f;
#pragma unroll
      for (int j = 0; j < 24; ++j) {
        const float v = isCol ? qkbuf[j][idx] : qkbuf[idx][j];
        m = fmaxf(m, v);
      }
      float s = 0.f;
#pragma unroll
      for (int j = 0; j < 24; ++j) {
        const float v = isCol ? qkbuf[j][idx] : qkbuf[idx][j];
        s += __expf(v - m);
      }
      const float rs = 1.f / s;
      if (isCol) {
        colmax[idx] = m;
        colrs[idx] = rs;
      } else {
        rowmax[idx] = m;
        rowrs[idx] = rs;
      }
    }
  }
  __syncthreads();

  // ---- a_k (transposed) and a_q (in place over qk) ----
  for (int p = lane; p < QL * KVL; p += 64) {
    const int r = p / KVL, kk = p % KVL;
    const float x = qkbuf[r][kk];
    akT[kk][r] = __expf(x - rowmax[r]) * rowrs[r];
    qkbuf[r][kk] = __expf(x - colmax[kk]) * colrs[kk];
  }
  __syncthreads();

  // ---- c_q[q][e] = sum_k a_q[q][k] * k_proj[k][e]; store into qc[:, 12:24] ----
  for (int p = lane; p < QL * DQ; p += 64) {
    const int r = p / DQ, e = p % DQ;
    float acc = 0.f;
#pragma unroll
    for (int kk = 0; kk < KVL; ++kk) acc += qkbuf[r][kk] * kp[kk][e];
    qcb[r][DQ + e] = acc;
  }
  __syncthreads();

  // ---- c_k[k][e] = sum_q a_k[q][k] * qc[q][e]  (overwrite qkbuf) ----
  for (int p = lane; p < KVL * 2 * DQ; p += 64) {
    const int kk = p / (2 * DQ), e = p % (2 * DQ);
    float acc = 0.f;
#pragma unroll
    for (int r = 0; r < QL; ++r) acc += akT[kk][r] * qcb[r][e];
    qkbuf[kk][e] = acc;
  }
  __syncthreads();

  // ---- attn[e][d] = bl[d] + sum_k c_k[k][e] * Wl[d][k]; coalesced store ----
  float* ob = out + (size_t)b * (2 * DQ * DQ);
  for (int p = lane; p < 2 * DQ * DQ; p += 64) {
    const int e = p / DQ, d = p % DQ;
    float acc = bll[d];
#pragma unroll
    for (int kk = 0; kk < KVL; ++kk) acc += qkbuf[kk][e] * Wl_l[d * KVL + kk];
    ob[p] = acc;
  }
}

extern "C" void kernel_launch(void* const* d_in, const int* in_sizes, int n_in,
                              void* d_out, int out_size, void* d_ws, size_t ws_size,
                              hipStream_t stream) {
  const float* q = (const float*)d_in[0];
  const float* k = (const float*)d_in[1];
  // d_in[2] = v : unused by the reference
  const float* Wq = (const float*)d_in[3];
  const float* bq = (const float*)d_in[4];
  const float* Wk = (const float*)d_in[5];
  const float* bk = (const float*)d_in[6];
  const float* Wl = (const float*)d_in[7];
  const float* bl = (const float*)d_in[8];
  float* out = (float*)d_out;

  const int B = in_sizes[0] / (24 * 12);
  coattn_kernel<<<B, 64, 0, stream>>>(q, k, Wq, bq, Wk, bk, Wl, bl, out);
}